// Round 5
// baseline (109.336 us; speedup 1.0000x reference)
//
#include <hip/hip_runtime.h>

// WeatherLSTM: B=4096 indep. sequences, T=512 steps, H=10, I=O=1.
// R3 layout: 32 lanes per element = 2 gate-halves x 16 lanes.
//   half0 (lanes <32): gates i,f for hidden unit k = lane&15
//   half1 (lanes>=32): gates g,o for hidden unit k
// Uniform stream: per-lane prescaled weights + per-lane fixup constants.
// Halves exchange activations via v_permlane32_swap (VALU-rate); its register
// convention is runtime-probed once (wave-uniform) -> template<bool PICKX>.
// h all-gather: 1 ds_write_b32 + float4/float2 LDS reads (broadcast, conflict-
// free, wave-private rows -> no barrier). 2048 waves = 2 per SIMD (TLP!).

#define NLOG2E (-1.4426950408889634f)

template<bool PICKX>
__device__ __forceinline__ float pickf(unsigned x, unsigned y) {
    return __uint_as_float(PICKX ? x : y);
}

template<bool PICKX>
__device__ __forceinline__ void lstm_run(
    const float* __restrict__ xe, int T,
    const float (&wh)[2][10], float wi0, float wi1, float bb0, float bb1,
    float fm, float fa, float* hrow, float (&h)[10])
{
    const int k = threadIdx.x & 15;
    #pragma unroll
    for (int j = 0; j < 10; ++j) h[j] = 0.0f;
    float c = 0.0f;

    float4 xv = *reinterpret_cast<const float4*>(xe);
    for (int s0 = 0; s0 < T; s0 += 4) {
        const int snext = (s0 + 4 < T) ? (s0 + 4) : s0;   // clamped prefetch
        const float4 xnext = *reinterpret_cast<const float4*>(xe + snext);
        #pragma unroll
        for (int ss = 0; ss < 4; ++ss) {
            const float xt = (&xv.x)[ss];

            // two gate dot products (prescaled: result is the exp2 argument)
            float aA0 = fmaf(xt, wi0, bb0);
            float aA1 = fmaf(xt, wi1, bb1);
            float aB0 = h[5] * wh[0][5];
            float aB1 = h[5] * wh[1][5];
            #pragma unroll
            for (int j = 0; j < 5; ++j) {
                aA0 = fmaf(h[j], wh[0][j], aA0);
                aA1 = fmaf(h[j], wh[1][j], aA1);
            }
            #pragma unroll
            for (int j = 6; j < 10; ++j) {
                aB0 = fmaf(h[j], wh[0][j], aB0);
                aB1 = fmaf(h[j], wh[1][j], aB1);
            }
            const float r0 = __builtin_amdgcn_rcpf(
                1.0f + __builtin_amdgcn_exp2f(aA0 + aB0));
            const float r1 = __builtin_amdgcn_rcpf(
                1.0f + __builtin_amdgcn_exp2f(aA1 + aB1));
            const float a0 = fmaf(fm, r0, fa);   // tanh fixup on g-gate lanes
            const float a1 = r1;

            // exchange with partner half (lane ^ 32); both outputs usable:
            // {x,y} = {value-from-lo-owner bcast, value-from-hi-owner bcast}
            auto w0 = __builtin_amdgcn_permlane32_swap(
                __float_as_uint(a0), __float_as_uint(a0), false, false);
            auto w1 = __builtin_amdgcn_permlane32_swap(
                __float_as_uint(a1), __float_as_uint(a1), false, false);
            const float iv = pickf<PICKX>(w0[0], w0[1]);  // i (from half0 a0)
            const float gv = pickf<PICKX>(w0[1], w0[0]);  // g (from half1 a0)
            const float fv = pickf<PICKX>(w1[0], w1[1]);  // f (from half0 a1)
            const float ov = pickf<PICKX>(w1[1], w1[0]);  // o (from half1 a1)

            // c/h maintained redundantly (bit-identical) in all 32 lanes
            c = fmaf(fv, c, iv * gv);
            const float e2 = __builtin_amdgcn_exp2f(c * (2.0f * NLOG2E));
            const float th = fmaf(2.0f, __builtin_amdgcn_rcpf(1.0f + e2), -1.0f);
            const float hown = ov * th;

            // h all-gather via wave-private LDS row (in-order DS pipe, no bar)
            hrow[k] = hown;
            const float4 h03 = *reinterpret_cast<const float4*>(hrow);
            const float4 h47 = *reinterpret_cast<const float4*>(hrow + 4);
            const float2 h89 = *reinterpret_cast<const float2*>(hrow + 8);
            h[0] = h03.x; h[1] = h03.y; h[2] = h03.z; h[3] = h03.w;
            h[4] = h47.x; h[5] = h47.y; h[6] = h47.z; h[7] = h47.w;
            h[8] = h89.x; h[9] = h89.y;
        }
        xv = xnext;
    }
}

__global__ __launch_bounds__(256, 2) void WeatherLSTM_kernel(
    const float* __restrict__ x,     // [B, T, 1]
    const float* __restrict__ W_ih,  // [40, 1]
    const float* __restrict__ W_hh,  // [40, 10]
    const float* __restrict__ b_ih,  // [40]
    const float* __restrict__ b_hh,  // [40]
    const float* __restrict__ W_fc,  // [1, 10]
    const float* __restrict__ b_fc,  // [1]
    float* __restrict__ out,         // [B, 1]
    int T)
{
    __shared__ float hsh[8][16];     // 8 elems/block, wave-private rows
    const int tid  = threadIdx.x;
    const int lane = tid & 63;
    const int wav  = tid >> 6;
    const int k    = lane & 15;      // hidden unit; active iff k < 10
    const int h1   = lane >> 5;      // gate half: 0 -> (i,f), 1 -> (g,o)
    const int eib  = wav * 2 + ((lane >> 4) & 1);
    const long e   = (long)blockIdx.x * 8 + eib;
    const bool act = (k < 10);

    // Own 2 gate rows, prescaled by the activation's exp2 factor:
    // sigmoid(v)=rcp(1+exp2(-v*log2e)); tanh(v)=2*rcp(1+exp2(-2v*log2e))-1
    float wh[2][10], wiv[2], bbv[2];
    #pragma unroll
    for (int p = 0; p < 2; ++p) {
        const int t = 2 * h1 + p;                       // gate index i,f,g,o
        const float s = (t == 2) ? (2.0f * NLOG2E) : NLOG2E;
        const int g = t * 10 + k;
        wiv[p] = act ? W_ih[g] * s : 0.0f;
        bbv[p] = act ? (b_ih[g] + b_hh[g]) * s : 0.0f;
        #pragma unroll
        for (int j = 0; j < 10; ++j)
            wh[p][j] = act ? W_hh[g * 10 + j] * s : 0.0f;
    }
    const float fm = h1 ? 2.0f : 1.0f;    // tanh fixup for gate g (t==2)
    const float fa = h1 ? -1.0f : 0.0f;

    // Probe permlane32_swap register convention once (wave-uniform result)
    auto pr = __builtin_amdgcn_permlane32_swap((unsigned)lane, (unsigned)lane,
                                               false, false);
    const bool pickx = ((int)pr[0] == (lane & 31));

    float h[10];
    if (pickx)
        lstm_run<true >(x + e * (long)T, T, wh, wiv[0], wiv[1], bbv[0], bbv[1],
                        fm, fa, &hsh[eib][0], h);
    else
        lstm_run<false>(x + e * (long)T, T, wh, wiv[0], wiv[1], bbv[0], bbv[1],
                        fm, fa, &hsh[eib][0], h);

    if (k == 0 && h1 == 0) {
        float o = b_fc[0];
        #pragma unroll
        for (int j = 0; j < 10; ++j)
            o = fmaf(h[j], W_fc[j], o);
        out[e] = o;
    }
}

extern "C" void kernel_launch(void* const* d_in, const int* in_sizes, int n_in,
                              void* d_out, int out_size, void* d_ws, size_t ws_size,
                              hipStream_t stream) {
    const float* x    = (const float*)d_in[0];
    const float* W_ih = (const float*)d_in[1];
    const float* W_hh = (const float*)d_in[2];
    const float* b_ih = (const float*)d_in[3];
    const float* b_hh = (const float*)d_in[4];
    const float* W_fc = (const float*)d_in[5];
    const float* b_fc = (const float*)d_in[6];
    float* out = (float*)d_out;

    const int B = out_size;          // 4096
    const int T = in_sizes[0] / B;   // 512

    dim3 grid(B / 8), block(256);    // 8 elems/block, 512 blocks, 2 waves/SIMD
    hipLaunchKernelGGL(WeatherLSTM_kernel, grid, block, 0, stream,
                       x, W_ih, W_hh, b_ih, b_hh, W_fc, b_fc, out, T);
}

// Round 7
// 92.444 us; speedup vs baseline: 1.1827x; 1.1827x over previous
//
#include <hip/hip_runtime.h>

// WeatherLSTM: B=4096 indep. sequences, T=512 steps, H=10, I=O=1.
// R6 = R5 + fix: clamp the LDS h-write slot for inactive lanes (k>=10).
// R5's hsh[16][24] row overflowed at 2k for k>=12 into the next group's row
// (racing h_0..h_7 with zeros). Now kw=min(k,10): inactive lanes write {0,0}
// to pair-slot 10 (never read). Layout: lane = hidden unit k, 16 lanes/elem,
// 4 elems/wave, 1024 waves = 1/SIMD. Issue cuts vs R2:
//  1) v_pk_fma_f32: 4 gate dot-chains packed into 2 (i,f) + (g,o)
//  2) paired-LDS h-gather: 1 ds_write_b64 + 5 broadcast ds_read_b128
//     (row stride 96B -> the 4 groups of a wave start on different banks)
//  3) fused reciprocals: ig=(1-pg)*rcp((1+pi)(1+pg)), o*tanh(c)=(1-pc)*
//     rcp((1+po)(1+pc)) -> 5 exp2 + 3 rcp per step

#define NLOG2E (-1.4426950408889634f)

typedef float f2 __attribute__((ext_vector_type(2)));
typedef float f4 __attribute__((ext_vector_type(4)));

__device__ __forceinline__ f2 pk_fma(f2 a, f2 b, f2 c) {
    f2 d;
    asm("v_pk_fma_f32 %0, %1, %2, %3" : "=v"(d) : "v"(a), "v"(b), "v"(c));
    return d;
}
__device__ __forceinline__ f2 pk_mul(f2 a, f2 b) {
    f2 d;
    asm("v_pk_mul_f32 %0, %1, %2" : "=v"(d) : "v"(a), "v"(b));
    return d;
}
__device__ __forceinline__ f2 pk_add(f2 a, f2 b) {
    f2 d;
    asm("v_pk_add_f32 %0, %1, %2" : "=v"(d) : "v"(a), "v"(b));
    return d;
}

__global__ __launch_bounds__(256, 1) void WeatherLSTM_kernel(
    const float* __restrict__ x,     // [B, T, 1]
    const float* __restrict__ W_ih,  // [40, 1]
    const float* __restrict__ W_hh,  // [40, 10]
    const float* __restrict__ b_ih,  // [40]
    const float* __restrict__ b_hh,  // [40]
    const float* __restrict__ W_fc,  // [1, 10]
    const float* __restrict__ b_fc,  // [1]
    float* __restrict__ out,         // [B, 1]
    int T)
{
    __shared__ float hsh[16][24];    // 16 groups x (10 pairs + slot10 + pad)
    const int tid = threadIdx.x;     // 256 = 16 groups of 16 lanes
    const int k   = tid & 15;        // hidden unit; active iff k < 10
    const int kw  = (k < 10) ? k : 10;  // clamped write slot (fix)
    const int grp = tid >> 4;
    const long e  = (long)blockIdx.x * 16 + grp;
    const bool act = (k < 10);
    float* hrow = &hsh[grp][0];

    // Packed, prescaled weights. Row scale: -L for sigmoid gates (i,f,o),
    // -2L for the tanh gate (g):  sigmoid(v)=rcp(1+exp2(-L v)) etc.
    const float sI = NLOG2E, sF = NLOG2E, sG = 2.0f * NLOG2E, sO = NLOG2E;
    f2 wIF[10], wGO[10], xwIF, xwGO, bIF, bGO;
    {
        const int gi = 0 * 10 + k, gf = 1 * 10 + k, gg = 2 * 10 + k, go = 3 * 10 + k;
        xwIF = act ? f2{W_ih[gi] * sI, W_ih[gf] * sF} : f2{0.f, 0.f};
        xwGO = act ? f2{W_ih[gg] * sG, W_ih[go] * sO} : f2{0.f, 0.f};
        bIF  = act ? f2{(b_ih[gi] + b_hh[gi]) * sI, (b_ih[gf] + b_hh[gf]) * sF}
                   : f2{0.f, 0.f};
        bGO  = act ? f2{(b_ih[gg] + b_hh[gg]) * sG, (b_ih[go] + b_hh[go]) * sO}
                   : f2{0.f, 0.f};
        #pragma unroll
        for (int j = 0; j < 10; ++j) {
            wIF[j] = act ? f2{W_hh[gi * 10 + j] * sI, W_hh[gf * 10 + j] * sF}
                         : f2{0.f, 0.f};
            wGO[j] = act ? f2{W_hh[gg * 10 + j] * sG, W_hh[go * 10 + j] * sO}
                         : f2{0.f, 0.f};
        }
    }
    // Inactive lanes: acc=0 -> p*=1 -> f=.5, ig=0, c=0, pc=1, h=0; they write
    // {0,0} to slot 10 (same addr, same value, never read). Harmless.

    f2 h2[10];                       // {h_j, h_j} pairs
    #pragma unroll
    for (int j = 0; j < 10; ++j) h2[j] = f2{0.f, 0.f};
    float c = 0.0f;

    const float* xe = x + e * (long)T;
    f4 xv = *reinterpret_cast<const f4*>(xe);
    for (int s0 = 0; s0 < T; s0 += 4) {
        const int snext = (s0 + 4 < T) ? (s0 + 4) : s0;     // clamped prefetch
        const f4 xnext = *reinterpret_cast<const f4*>(xe + snext);
        #pragma unroll
        for (int ss = 0; ss < 4; ++ss) {
            const float xt = xv[ss];
            const f2 xt2 = f2{xt, xt};

            // packed gate dots, 4 independent chains for ILP
            f2 aIF0 = pk_fma(xt2, xwIF, bIF);
            f2 aGO0 = pk_fma(xt2, xwGO, bGO);
            f2 aIF1 = pk_mul(h2[5], wIF[5]);
            f2 aGO1 = pk_mul(h2[5], wGO[5]);
            #pragma unroll
            for (int j = 0; j < 5; ++j) {
                aIF0 = pk_fma(h2[j], wIF[j], aIF0);
                aGO0 = pk_fma(h2[j], wGO[j], aGO0);
            }
            #pragma unroll
            for (int j = 6; j < 10; ++j) {
                aIF1 = pk_fma(h2[j], wIF[j], aIF1);
                aGO1 = pk_fma(h2[j], wGO[j], aGO1);
            }
            const f2 aIF = pk_add(aIF0, aIF1);
            const f2 aGO = pk_add(aGO0, aGO1);

            // activations with fused reciprocals (5 exp2 + 3 rcp)
            const float pi = __builtin_amdgcn_exp2f(aIF[0]);
            const float pf = __builtin_amdgcn_exp2f(aIF[1]);
            const float pg = __builtin_amdgcn_exp2f(aGO[0]);
            const float po = __builtin_amdgcn_exp2f(aGO[1]);
            const float f  = __builtin_amdgcn_rcpf(1.0f + pf);
            const float ig = (1.0f - pg) *
                __builtin_amdgcn_rcpf((1.0f + pi) * (1.0f + pg));
            c = fmaf(f, c, ig);
            const float pc = __builtin_amdgcn_exp2f(c * (2.0f * NLOG2E));
            const float hown = (1.0f - pc) *
                __builtin_amdgcn_rcpf((1.0f + po) * (1.0f + pc));

            // paired h all-gather: 1 ds_write_b64 + 5 broadcast ds_read_b128
            *reinterpret_cast<f2*>(hrow + 2 * kw) = f2{hown, hown};
            #pragma unroll
            for (int r = 0; r < 5; ++r) {
                const f4 v = *reinterpret_cast<const f4*>(hrow + 4 * r);
                h2[2 * r]     = f2{v[0], v[1]};
                h2[2 * r + 1] = f2{v[2], v[3]};
            }
        }
        xv = xnext;
    }

    if (k == 0) {
        float o = b_fc[0];
        #pragma unroll
        for (int j = 0; j < 10; ++j)
            o = fmaf(h2[j][0], W_fc[j], o);
        out[e] = o;
    }
}

extern "C" void kernel_launch(void* const* d_in, const int* in_sizes, int n_in,
                              void* d_out, int out_size, void* d_ws, size_t ws_size,
                              hipStream_t stream) {
    const float* x    = (const float*)d_in[0];
    const float* W_ih = (const float*)d_in[1];
    const float* W_hh = (const float*)d_in[2];
    const float* b_ih = (const float*)d_in[3];
    const float* b_hh = (const float*)d_in[4];
    const float* W_fc = (const float*)d_in[5];
    const float* b_fc = (const float*)d_in[6];
    float* out = (float*)d_out;

    const int B = out_size;          // 4096
    const int T = in_sizes[0] / B;   // 512

    dim3 grid(B / 16), block(256);   // 16 elems/block, 256 blocks = 1 per CU
    hipLaunchKernelGGL(WeatherLSTM_kernel, grid, block, 0, stream,
                       x, W_ih, W_hh, b_ih, b_hh, W_fc, b_fc, out, T);
}